// Round 3
// baseline (784.746 us; speedup 1.0000x reference)
//
#include <hip/hip_runtime.h>
#include <hip/hip_bf16.h>

#define TT 4096
#define BB 256
#define DD 3
#define UU 8

// ---------- fast activations ----------
#if defined(__has_builtin)
#if __has_builtin(__builtin_amdgcn_exp2f) && __has_builtin(__builtin_amdgcn_rcpf)
#define FAST_EXP2(x) __builtin_amdgcn_exp2f(x)
#define FAST_RCP(x)  __builtin_amdgcn_rcpf(x)
#endif
#endif
#ifndef FAST_EXP2
#define FAST_EXP2(x) exp2f(x)
#define FAST_RCP(x)  (1.0f / (x))
#endif

#define NLOG2E  (-1.4426950408889634f)
#define P2LOG2E ( 2.8853900817779268f)

__device__ __forceinline__ float fsig(float x) {   // used by fallback only
    float e = FAST_EXP2(NLOG2E * x);
    return FAST_RCP(1.0f + e);
}

// ---------- DPP helpers ----------
template <int CTRL>
__device__ __forceinline__ float dpp_f(float v) {
    int i = __builtin_bit_cast(int, v);
    i = __builtin_amdgcn_update_dpp(0, i, CTRL, 0xF, 0xF, true);
    return __builtin_bit_cast(float, i);
}
template <int CTRL, int RM>
__device__ __forceinline__ float dpp_add(float x) {
    int t = __builtin_amdgcn_update_dpp(0, __builtin_bit_cast(int, x), CTRL, RM, 0xF, true);
    return x + __builtin_bit_cast(float, t);
}
// wave64 inclusive scan, pure VALU (row_shr + bcast15/31)
__device__ __forceinline__ float wave_incl_scan(float v) {
    v = dpp_add<0x111, 0xF>(v);   // row_shr:1
    v = dpp_add<0x112, 0xF>(v);   // row_shr:2
    v = dpp_add<0x114, 0xF>(v);   // row_shr:4
    v = dpp_add<0x118, 0xF>(v);   // row_shr:8
    v = dpp_add<0x142, 0xA>(v);   // row_bcast:15 -> rows 1,3
    v = dpp_add<0x143, 0xC>(v);   // row_bcast:31 -> rows 2,3
    return v;
}

// ---------- Kernel A: signature + forget gate + scaled input projection ----------
// ws layout: [t][b][u] float4 = {-L*gi_pre, 2L*gc_pre, -L*go_pre, f_sigmoided}
__global__ __launch_bounds__(256) void sig_pre_kernel(
    const float* __restrict__ x,     // (B,T,3)
    const float* __restrict__ Wi,    // (3,24)
    const float* __restrict__ Wf,    // (21,8)
    const float* __restrict__ bias,  // (32)
    float* __restrict__ ws)
{
    __shared__ float sWf[168];
    __shared__ float sWi[72];
    __shared__ float sB[32];
    __shared__ float tot1[4 * 4];
    __shared__ float tot2[4 * 16];

    const int tid = threadIdx.x;
    const int b = blockIdx.x;
    if (tid < 168) sWf[tid] = NLOG2E * Wf[tid];
    if (tid < 72) {
        int col = tid % 24;
        float s = (col < 8) ? NLOG2E : (col < 16) ? P2LOG2E : NLOG2E;
        sWi[tid] = s * Wi[tid];
    }
    if (tid < 32) {
        float s = (tid < 16) ? NLOG2E : (tid < 24) ? P2LOG2E : NLOG2E;
        sB[tid] = s * bias[tid];
    }
    __syncthreads();

    const float dtc = 1.0f / 4095.0f;
    const int t0 = tid * 16;
    const int lid = tid & 63;
    const int wv = tid >> 6;
    const float* xb = x + (size_t)b * TT * DD;

    // ---- vectorized load: 16 steps x 3 floats = 12 float4, kept in regs ----
    float xs[48];
    {
        const float4* xv = (const float4*)(xb + (size_t)t0 * 3);
        #pragma unroll
        for (int k = 0; k < 12; ++k) {
            float4 v = xv[k];
            xs[k * 4 + 0] = v.x; xs[k * 4 + 1] = v.y;
            xs[k * 4 + 2] = v.z; xs[k * 4 + 3] = v.w;
        }
    }
    float pp0, pp1, pp2;   // x[t0-1] (x[0] for tid==0)
    if (tid == 0) { pp0 = xs[0]; pp1 = xs[1]; pp2 = xs[2]; }
    else { pp0 = xb[t0 * 3 - 3]; pp1 = xb[t0 * 3 - 2]; pp2 = xb[t0 * 3 - 1]; }

    // ---- pass 1: chunk-local L1 (4) and L2 (16) sums ----
    float l1[4] = {0.f, 0.f, 0.f, 0.f};
    float l2[16];
    #pragma unroll
    for (int i = 0; i < 16; ++i) l2[i] = 0.f;
    {
        float xp0 = pp0, xp1 = pp1, xp2 = pp2;
        #pragma unroll
        for (int i = 0; i < 16; ++i) {
            float c0 = xs[i * 3], c1 = xs[i * 3 + 1], c2 = xs[i * 3 + 2];
            float d0 = (tid == 0 && i == 0) ? 0.f : dtc;
            float dxv[4] = {d0, c0 - xp0, c1 - xp1, c2 - xp2};
            #pragma unroll
            for (int r = 0; r < 4; ++r) {
                float tr = l1[r] + 0.5f * dxv[r];
                #pragma unroll
                for (int cc = 0; cc < 4; ++cc)
                    l2[r * 4 + cc] = fmaf(tr, dxv[cc], l2[r * 4 + cc]);
            }
            #pragma unroll
            for (int r = 0; r < 4; ++r) l1[r] += dxv[r];
            xp0 = c0; xp1 = c1; xp2 = c2;
        }
    }

    // ---- L1 block-exclusive scan (DPP wave scan + one LDS combine) ----
    float I1[4], O1[4];
    #pragma unroll
    for (int r = 0; r < 4; ++r) {
        I1[r] = wave_incl_scan(l1[r]);
        if (lid == 63) tot1[wv * 4 + r] = I1[r];
    }
    __syncthreads();
    #pragma unroll
    for (int r = 0; r < 4; ++r) {
        float off = 0.f;
        for (int w = 0; w < wv; ++w) off += tot1[w * 4 + r];
        O1[r] = off + I1[r] - l1[r];
    }

    // ---- L2 block-exclusive scan of (S2 + O1 (x) S1) ----
    float I2[16], cin[16], O2[16];
    #pragma unroll
    for (int rc = 0; rc < 16; ++rc) {
        float c2v = l2[rc] + O1[rc >> 2] * l1[rc & 3];
        cin[rc] = c2v;
        I2[rc] = wave_incl_scan(c2v);
        if (lid == 63) tot2[wv * 16 + rc] = I2[rc];
    }
    __syncthreads();
    #pragma unroll
    for (int rc = 0; rc < 16; ++rc) {
        float off = 0.f;
        for (int w = 0; w < wv; ++w) off += tot2[w * 16 + rc];
        O2[rc] = off + I2[rc] - cin[rc];
    }

    // ---- pass 2: walk chunk, emit f + scaled pre-gates ----
    #pragma unroll
    for (int r = 0; r < 4; ++r) l1[r] = O1[r];
    #pragma unroll
    for (int i = 0; i < 16; ++i) l2[i] = O2[i];

    float xp0 = pp0, xp1 = pp1, xp2 = pp2;
    #pragma unroll
    for (int i2 = 0; i2 < 16; ++i2) {
        const int t = t0 + i2;
        float c0 = xs[i2 * 3], c1 = xs[i2 * 3 + 1], c2 = xs[i2 * 3 + 2];
        float d0 = (tid == 0 && i2 == 0) ? 0.f : dtc;
        float dxv[4] = {d0, c0 - xp0, c1 - xp1, c2 - xp2};
        #pragma unroll
        for (int r = 0; r < 4; ++r) {
            float tr = l1[r] + 0.5f * dxv[r];
            #pragma unroll
            for (int cc = 0; cc < 4; ++cc)
                l2[r * 4 + cc] = fmaf(tr, dxv[cc], l2[r * 4 + cc]);
        }
        #pragma unroll
        for (int r = 0; r < 4; ++r) l1[r] += dxv[r];
        xp0 = c0; xp1 = c1; xp2 = c2;

        const float scale = (t == 0) ? 1.0f : (4095.0f / (float)t);
        // forget dot in raw signature space, scale once per unit
        float fa[8];
        #pragma unroll
        for (int u = 0; u < 8; ++u) fa[u] = sWf[u];       // constant-term (sig_0 = 1 before scale)
        #pragma unroll
        for (int r = 0; r < 4; ++r) {
            float s = l1[r];
            #pragma unroll
            for (int u = 0; u < 8; ++u) fa[u] = fmaf(s, sWf[(1 + r) * 8 + u], fa[u]);
        }
        #pragma unroll
        for (int rc = 0; rc < 16; ++rc) {
            float s = l2[rc];
            #pragma unroll
            for (int u = 0; u < 8; ++u) fa[u] = fmaf(s, sWf[(5 + rc) * 8 + u], fa[u]);
        }
        // scaled input projection + bias
        float g[24];
        #pragma unroll
        for (int u = 0; u < 8; ++u) {
            g[u] = sB[u]; g[8 + u] = sB[16 + u]; g[16 + u] = sB[24 + u];
        }
        #pragma unroll
        for (int gg = 0; gg < 24; ++gg) {
            g[gg] = fmaf(c0, sWi[gg], g[gg]);
            g[gg] = fmaf(c1, sWi[24 + gg], g[gg]);
            g[gg] = fmaf(c2, sWi[48 + gg], g[gg]);
        }
        float4* wp = (float4*)ws + ((size_t)t * BB + b) * UU;
        #pragma unroll
        for (int u = 0; u < 8; ++u) {
            float fav = fmaf(scale, fa[u], sB[8 + u]);      // -L*(sig.Wf + b_f)
            float f = FAST_RCP(1.0f + FAST_EXP2(fav));      // sigmoid
            wp[u] = make_float4(g[u], g[8 + u], g[16 + u], f);
        }
    }
}

// ---------- Kernel B: sequential LSTM scan, DPP butterfly + merged activations ----------
__global__ __launch_bounds__(64) void lstm_scan_full(
    const float* __restrict__ ws, const float* __restrict__ Wr,
    float* __restrict__ out)
{
    const int lane = threadIdx.x;
    const int u = lane & 7;
    const int b = blockIdx.x * 8 + (lane >> 3);
    // scaled weights: wa,wc *= -log2e ; wb *= 2log2e (source unit j = u^m)
    float wa[8], wb[8], wc[8];
    #pragma unroll
    for (int m = 0; m < 8; ++m) {
        int j = u ^ m;
        wa[m] = NLOG2E  * Wr[j * 24 + u];
        wb[m] = P2LOG2E * Wr[j * 24 + 8 + u];
        wc[m] = NLOG2E  * Wr[j * 24 + 16 + u];
    }
    const float4* gp = (const float4*)ws + (size_t)b * 8 + u;  // + t*2048
    float4 buf[8];                                             // prefetch ring depth 8
    #pragma unroll
    for (int p = 0; p < 8; ++p) buf[p] = gp[(size_t)p * 2048];
    float h = 0.f, c = 0.f;
    float* op = out + (size_t)b * TT * 8 + u;

    auto step = [&](int t, float4 g) {
        // DPP xor-butterfly broadcast of h across the 8-lane group
        float h1 = dpp_f<0xB1>(h);    // xor 1
        float h2 = dpp_f<0x4E>(h);    // xor 2
        float h3 = dpp_f<0x1B>(h);    // xor 3
        float h7 = dpp_f<0x141>(h);   // xor 7 (row_half_mirror)
        float h6 = dpp_f<0xB1>(h7);   // xor 6
        float h5 = dpp_f<0x4E>(h7);   // xor 5
        float h4 = dpp_f<0x1B>(h7);   // xor 4
        float gi = fmaf(h, wa[0], g.x), giB = h4 * wa[4];
        float gc = fmaf(h, wb[0], g.y), gcB = h4 * wb[4];
        float go = fmaf(h, wc[0], g.z), goB = h4 * wc[4];
        gi = fmaf(h1, wa[1], gi);  giB = fmaf(h5, wa[5], giB);
        gc = fmaf(h1, wb[1], gc);  gcB = fmaf(h5, wb[5], gcB);
        go = fmaf(h1, wc[1], go);  goB = fmaf(h5, wc[5], goB);
        gi = fmaf(h2, wa[2], gi);  giB = fmaf(h6, wa[6], giB);
        gc = fmaf(h2, wb[2], gc);  gcB = fmaf(h6, wb[6], gcB);
        go = fmaf(h2, wc[2], go);  goB = fmaf(h6, wc[6], goB);
        gi = fmaf(h3, wa[3], gi);  giB = fmaf(h7, wa[7], giB);
        gc = fmaf(h3, wb[3], gc);  gcB = fmaf(h7, wb[7], gcB);
        go = fmaf(h3, wc[3], go);  goB = fmaf(h7, wc[7], goB);
        gi += giB; gc += gcB; go += goB;
        // gi = -L*i_pre, gc = 2L*c_pre, go = -L*o_pre
        float ei = FAST_EXP2(gi);
        float ec = FAST_EXP2(gc);
        float eo = FAST_EXP2(go);
        // sig(i)*tanh(c_hat) = (ec-1)/((1+ei)(1+ec))
        float r1 = FAST_RCP((1.0f + ei) * (1.0f + ec));
        c = fmaf(g.w, c, (ec - 1.0f) * r1);
        // h = sig(o)*tanh(c) = (e2c-1)/((1+eo)(1+e2c)), clamp exp arg
        float s3 = fminf(P2LOG2E * c, 63.0f);
        float e2c = FAST_EXP2(s3);
        float r2 = FAST_RCP((1.0f + eo) * (1.0f + e2c));
        h = (e2c - 1.0f) * r2;
        op[(size_t)t * 8] = h;
    };

    for (int tb = 0; tb + 8 < TT; tb += 8) {
        #pragma unroll
        for (int j = 0; j < 8; ++j) {
            const int t = tb + j;
            float4 g = buf[j];
            buf[j] = gp[(size_t)(t + 8) * 2048];   // prefetch depth 8
            step(t, g);
        }
    }
    #pragma unroll
    for (int j = 0; j < 8; ++j) step(TT - 8 + j, buf[j]);
}

// ---------- Fallback: no-scratch single kernel (raw weights, original math) ----------
__global__ __launch_bounds__(64) void lstm_scan_ultra(
    const float* __restrict__ x, const float* __restrict__ Wi,
    const float* __restrict__ Wr, const float* __restrict__ Wf,
    const float* __restrict__ bias, float* __restrict__ out)
{
    const int lane = threadIdx.x;
    const int u = lane & 7;
    const int q = lane >> 3;
    const int b = blockIdx.x * 8 + q;
    float wa[8], wb[8], wc[8];
    #pragma unroll
    for (int m = 0; m < 8; ++m) {
        int j = u ^ m;
        wa[m] = Wr[j * 24 + u];
        wb[m] = Wr[j * 24 + 8 + u];
        wc[m] = Wr[j * 24 + 16 + u];
    }
    float wia[3], wib[3], wic[3];
    #pragma unroll
    for (int k = 0; k < 3; ++k) {
        wia[k] = Wi[k * 24 + u];
        wib[k] = Wi[k * 24 + 8 + u];
        wic[k] = Wi[k * 24 + 16 + u];
    }
    float wf[21];
    #pragma unroll
    for (int j = 0; j < 21; ++j) wf[j] = Wf[j * 8 + u];
    const float bi = bias[u], bf = bias[8 + u], bc = bias[16 + u], bo = bias[24 + u];
    const float* xb = x + (size_t)b * TT * 3;
    float l1[4] = {0.f, 0.f, 0.f, 0.f};
    float l2[16];
    #pragma unroll
    for (int i = 0; i < 16; ++i) l2[i] = 0.f;
    float xp0 = xb[0], xp1 = xb[1], xp2 = xb[2];
    float h = 0.f, c = 0.f;
    float* op = out + (size_t)b * TT * 8 + u;
    const float dtc = 1.0f / 4095.0f;
    for (int t = 0; t < TT; ++t) {
        float c0 = xb[t * 3 + 0], c1 = xb[t * 3 + 1], c2 = xb[t * 3 + 2];
        if (t > 0) {
            float dxv[4] = {dtc, c0 - xp0, c1 - xp1, c2 - xp2};
            #pragma unroll
            for (int r = 0; r < 4; ++r) {
                float tr = l1[r] + 0.5f * dxv[r];
                #pragma unroll
                for (int cc = 0; cc < 4; ++cc)
                    l2[r * 4 + cc] = fmaf(tr, dxv[cc], l2[r * 4 + cc]);
            }
            #pragma unroll
            for (int r = 0; r < 4; ++r) l1[r] += dxv[r];
        }
        xp0 = c0; xp1 = c1; xp2 = c2;
        const float scale = (t == 0) ? 1.0f : (4095.0f / (float)t);
        float dot = wf[0];
        #pragma unroll
        for (int r = 0; r < 4; ++r) dot = fmaf(l1[r], wf[1 + r], dot);
        #pragma unroll
        for (int rc = 0; rc < 16; ++rc) dot = fmaf(l2[rc], wf[5 + rc], dot);
        float fv = fsig(fmaf(scale, dot, bf));
        float gi = bi, gc = bc, go = bo;
        gi = fmaf(c0, wia[0], gi); gi = fmaf(c1, wia[1], gi); gi = fmaf(c2, wia[2], gi);
        gc = fmaf(c0, wib[0], gc); gc = fmaf(c1, wib[1], gc); gc = fmaf(c2, wib[2], gc);
        go = fmaf(c0, wic[0], go); go = fmaf(c1, wic[1], go); go = fmaf(c2, wic[2], go);
        float h1 = dpp_f<0xB1>(h);
        float h2 = dpp_f<0x4E>(h);
        float h3 = dpp_f<0x1B>(h);
        float h7 = dpp_f<0x141>(h);
        float h6 = dpp_f<0xB1>(h7);
        float h5 = dpp_f<0x4E>(h7);
        float h4 = dpp_f<0x1B>(h7);
        gi = fmaf(h, wa[0], gi); gi = fmaf(h1, wa[1], gi); gi = fmaf(h2, wa[2], gi); gi = fmaf(h3, wa[3], gi);
        gi = fmaf(h4, wa[4], gi); gi = fmaf(h5, wa[5], gi); gi = fmaf(h6, wa[6], gi); gi = fmaf(h7, wa[7], gi);
        gc = fmaf(h, wb[0], gc); gc = fmaf(h1, wb[1], gc); gc = fmaf(h2, wb[2], gc); gc = fmaf(h3, wb[3], gc);
        gc = fmaf(h4, wb[4], gc); gc = fmaf(h5, wb[5], gc); gc = fmaf(h6, wb[6], gc); gc = fmaf(h7, wb[7], gc);
        go = fmaf(h, wc[0], go); go = fmaf(h1, wc[1], go); go = fmaf(h2, wc[2], go); go = fmaf(h3, wc[3], go);
        go = fmaf(h4, wc[4], go); go = fmaf(h5, wc[5], go); go = fmaf(h6, wc[6], go); go = fmaf(h7, wc[7], go);
        float iv = fsig(gi);
        float cv = 1.0f - 2.0f * FAST_RCP(1.0f + FAST_EXP2(P2LOG2E * gc));
        float ov = fsig(go);
        c = fmaf(fv, c, iv * cv);
        float s3 = fminf(P2LOG2E * c, 63.0f);
        h = ov * (1.0f - 2.0f * FAST_RCP(1.0f + FAST_EXP2(s3)));
        op[(size_t)t * 8] = h;
    }
}

extern "C" void kernel_launch(void* const* d_in, const int* in_sizes, int n_in,
                              void* d_out, int out_size, void* d_ws, size_t ws_size,
                              hipStream_t stream) {
    const float* x    = (const float*)d_in[0];  // (256,4096,3)
    const float* Wi   = (const float*)d_in[1];  // (3,24)
    const float* Wr   = (const float*)d_in[2];  // (8,24)
    const float* Wf   = (const float*)d_in[3];  // (21,8)
    const float* bias = (const float*)d_in[4];  // (32,)
    float* out = (float*)d_out;                 // (256,4096,8)

    const size_t need = (size_t)TT * BB * UU * 4 * sizeof(float);  // 128 MiB
    if (ws_size >= need) {
        sig_pre_kernel<<<dim3(BB), dim3(256), 0, stream>>>(x, Wi, Wf, bias, (float*)d_ws);
        lstm_scan_full<<<dim3(BB / 8), dim3(64), 0, stream>>>((const float*)d_ws, Wr, out);
    } else {
        lstm_scan_ultra<<<dim3(BB / 8), dim3(64), 0, stream>>>(x, Wi, Wr, Wf, bias, out);
    }
}